// Round 3
// baseline (371.584 us; speedup 1.0000x reference)
//
#include <hip/hip_runtime.h>
#include <hip/hip_cooperative_groups.h>

#define BNEPS 1e-5f

// ---------------------------------------------------------------------------
// The reference network's output is batch-constant: binarize(relu(x)) == +1
// everywhere, so the fire module's outputs are data-independent. We compute
// feat F[128] and logits L[1000] once, then broadcast over the 8192 rows.
//
// ws layout (floats): [0..1000) = L, [1024..1152) = F, [1152..1280) = Cc
//
// Primary path: ONE cooperative kernel, 3 phases split by grid.sync(),
// eliminating two dispatch boundaries. Fallback: the proven 3-kernel chain.
// ---------------------------------------------------------------------------

namespace cg = cooperative_groups;

__device__ __forceinline__ float wave_reduce(float acc) {
    #pragma unroll
    for (int off = 32; off > 0; off >>= 1)
        acc += __shfl_down(acc, off);
    return acc;
}

// ============================ fused cooperative ============================

__global__ __launch_bounds__(256, 4) void fused_all(
    const float* __restrict__ w_e1, const float* __restrict__ b_e1,
    const float* __restrict__ w_pw,
    const float* __restrict__ bnpw_g, const float* __restrict__ bnpw_b,
    const float* __restrict__ bnpw_m, const float* __restrict__ bnpw_v,
    const float* __restrict__ bnf_g, const float* __restrict__ bnf_b,
    const float* __restrict__ bnf_m, const float* __restrict__ bnf_v,
    const float* __restrict__ w1, const float* __restrict__ b1,
    const float* __restrict__ bnc_g, const float* __restrict__ bnc_b,
    const float* __restrict__ bnc_m, const float* __restrict__ bnc_v,
    const float* __restrict__ w2, const float* __restrict__ b2,
    float* __restrict__ ws, float* __restrict__ out)
{
    cg::grid_group grid = cg::this_grid();

    __shared__ __align__(16) float e1c[128];
    __shared__ __align__(16) float e3c[128];
    __shared__ __align__(16) float hb[2304];
    __shared__ __align__(16) float sC[128];
    __shared__ float red[4];

    const int tid = threadIdx.x;
    const int bid = blockIdx.x;

    // ---- phase 1: blocks 0..127 compute F[o] and Cc[o] ----
    if (bid < 128) {
        const int o = bid;
        if (tid < 128) {
            const float4* we = reinterpret_cast<const float4*>(w_e1 + tid * 32);
            const float4* wp = reinterpret_cast<const float4*>(w_pw + tid * 32);
            float s = 0.f, p = 0.f;
            #pragma unroll
            for (int q = 0; q < 8; ++q) {
                float4 a = we[q], b = wp[q];
                s += ((a.x >= 0.f) ? 1.f : -1.f) + ((a.y >= 0.f) ? 1.f : -1.f)
                   + ((a.z >= 0.f) ? 1.f : -1.f) + ((a.w >= 0.f) ? 1.f : -1.f);
                p += ((b.x >= 0.f) ? 1.f : -1.f) + ((b.y >= 0.f) ? 1.f : -1.f)
                   + ((b.z >= 0.f) ? 1.f : -1.f) + ((b.w >= 0.f) ? 1.f : -1.f);
            }
            e1c[tid] = fmaxf(s + b_e1[tid], 0.f);
            float inv = bnpw_g[tid] * rsqrtf(bnpw_v[tid] + BNEPS);
            e3c[tid] = fmaxf((p - bnpw_m[tid]) * inv + bnpw_b[tid], 0.f);
        }
        __syncthreads();

        #pragma unroll
        for (int r = 0; r < 9; ++r) {
            int f = r * 256 + tid;
            int ch = f / 9;
            float v = (ch < 128) ? e1c[ch] : e3c[ch - 128];
            float inv = bnf_g[f] * rsqrtf(bnf_v[f] + BNEPS);
            hb[f] = (v - bnf_m[f]) * inv + bnf_b[f];
        }
        __syncthreads();

        const float4* __restrict__ w1r = reinterpret_cast<const float4*>(w1 + o * 2304);
        const float4* __restrict__ hb4 = reinterpret_cast<const float4*>(hb);
        float acc = 0.f;
        for (int j = tid; j < 576; j += 256) {
            float4 w = w1r[j];
            float4 h = hb4[j];
            acc += w.x * h.x + w.y * h.y + w.z * h.z + w.w * h.w;
        }
        acc = wave_reduce(acc);
        const int lane = tid & 63, wave = tid >> 6;
        if (lane == 0) red[wave] = acc;
        __syncthreads();
        if (tid == 0) {
            float F = (red[0] + red[1]) + (red[2] + red[3]) + b1[o];
            ws[1024 + o] = F;
            float r = fmaxf(F, 0.f);
            float inv = bnc_g[o] * rsqrtf(bnc_v[o] + BNEPS);
            ws[1152 + o] = (r - bnc_m[o]) * inv + bnc_b[o];
        }
    }
    __threadfence();
    grid.sync();

    // ---- phase 2: blocks 0..249 compute logits, one wave per logit ----
    if (bid < 250) {
        if (tid < 128) sC[tid] = ws[1152 + tid];
        __syncthreads();
        const int lane = tid & 63, wave = tid >> 6;
        const int n = bid * 4 + wave;    // 250*4 = 1000
        const float2* __restrict__ w2r = reinterpret_cast<const float2*>(w2 + n * 128);
        float2 w = w2r[lane];
        float acc = w.x * sC[2 * lane] + w.y * sC[2 * lane + 1];
        acc = wave_reduce(acc);
        if (lane == 0) ws[n] = acc + b2[n];
    }
    __threadfence();
    grid.sync();

    // ---- phase 3: broadcast ----
    __shared__ __align__(16) float sL[1000];
    __shared__ __align__(16) float sF[128];
    for (int i = tid; i < 1000; i += 256) sL[i] = ws[i];
    if (tid < 128) sF[tid] = ws[1024 + tid];
    __syncthreads();

    const float4* sL4 = reinterpret_cast<const float4*>(sL);
    const float4* sF4 = reinterpret_cast<const float4*>(sF);
    float4* out4 = reinterpret_cast<float4*>(out);

    const int TOT = 2310144;   // 9,240,576 floats / 4
    const int LOG = 2048000;   // 8,192,000 floats / 4 (logits section)

    for (int i = bid * 256 + tid; i < TOT; i += gridDim.x * 256) {
        float4 v;
        if (i < LOG) v = sL4[i % 250];
        else         v = sF4[(i - LOG) & 31];
        out4[i] = v;
    }
}

// ============================ fallback kernels =============================

__global__ __launch_bounds__(256) void feat_kernel(
    const float* __restrict__ w_e1, const float* __restrict__ b_e1,
    const float* __restrict__ w_pw,
    const float* __restrict__ bnpw_g, const float* __restrict__ bnpw_b,
    const float* __restrict__ bnpw_m, const float* __restrict__ bnpw_v,
    const float* __restrict__ bnf_g, const float* __restrict__ bnf_b,
    const float* __restrict__ bnf_m, const float* __restrict__ bnf_v,
    const float* __restrict__ w1, const float* __restrict__ b1,
    const float* __restrict__ bnc_g, const float* __restrict__ bnc_b,
    const float* __restrict__ bnc_m, const float* __restrict__ bnc_v,
    float* __restrict__ ws)
{
    __shared__ __align__(16) float e1c[128];
    __shared__ __align__(16) float e3c[128];
    __shared__ __align__(16) float hb[2304];
    __shared__ float red[4];

    const int tid = threadIdx.x;
    const int o = blockIdx.x;

    if (tid < 128) {
        float s = 0.f;
        #pragma unroll
        for (int c = 0; c < 32; ++c)
            s += (w_e1[tid * 32 + c] >= 0.f) ? 1.f : -1.f;
        e1c[tid] = fmaxf(s + b_e1[tid], 0.f);

        float p = 0.f;
        #pragma unroll
        for (int c = 0; c < 32; ++c)
            p += (w_pw[tid * 32 + c] >= 0.f) ? 1.f : -1.f;
        float inv = bnpw_g[tid] * rsqrtf(bnpw_v[tid] + BNEPS);
        e3c[tid] = fmaxf((p - bnpw_m[tid]) * inv + bnpw_b[tid], 0.f);
    }
    __syncthreads();

    for (int f = tid; f < 2304; f += 256) {
        int ch = f / 9;
        float v = (ch < 128) ? e1c[ch] : e3c[ch - 128];
        float inv = bnf_g[f] * rsqrtf(bnf_v[f] + BNEPS);
        hb[f] = (v - bnf_m[f]) * inv + bnf_b[f];
    }
    __syncthreads();

    const float4* __restrict__ w1r = reinterpret_cast<const float4*>(w1 + o * 2304);
    const float4* __restrict__ hb4 = reinterpret_cast<const float4*>(hb);
    float acc = 0.f;
    for (int j = tid; j < 576; j += 256) {
        float4 w = w1r[j];
        float4 h = hb4[j];
        acc += w.x * h.x + w.y * h.y + w.z * h.z + w.w * h.w;
    }
    acc = wave_reduce(acc);
    const int lane = tid & 63, wave = tid >> 6;
    if (lane == 0) red[wave] = acc;
    __syncthreads();
    if (tid == 0) {
        float F = (red[0] + red[1]) + (red[2] + red[3]) + b1[o];
        ws[1024 + o] = F;
        float r = fmaxf(F, 0.f);
        float inv = bnc_g[o] * rsqrtf(bnc_v[o] + BNEPS);
        ws[1152 + o] = (r - bnc_m[o]) * inv + bnc_b[o];
    }
}

__global__ __launch_bounds__(256) void logits_kernel(
    const float* __restrict__ w2, const float* __restrict__ b2,
    float* __restrict__ ws)
{
    __shared__ __align__(16) float sC[128];
    const int tid = threadIdx.x;
    if (tid < 128) sC[tid] = ws[1152 + tid];
    __syncthreads();

    const int lane = tid & 63, wave = tid >> 6;
    const int n = blockIdx.x * 4 + wave;
    const float2* __restrict__ w2r = reinterpret_cast<const float2*>(w2 + n * 128);
    float2 w = w2r[lane];
    float acc = w.x * sC[2 * lane] + w.y * sC[2 * lane + 1];
    acc = wave_reduce(acc);
    if (lane == 0) ws[n] = acc + b2[n];
}

__global__ __launch_bounds__(256) void broadcast_out(
    const float* __restrict__ ws, float* __restrict__ out)
{
    __shared__ __align__(16) float sL[1000];
    __shared__ __align__(16) float sF[128];
    const int tid = threadIdx.x;
    for (int i = tid; i < 1000; i += 256) sL[i] = ws[i];
    if (tid < 128) sF[tid] = ws[1024 + tid];
    __syncthreads();

    const float4* sL4 = reinterpret_cast<const float4*>(sL);
    const float4* sF4 = reinterpret_cast<const float4*>(sF);
    float4* out4 = reinterpret_cast<float4*>(out);

    const int TOT = 2310144;
    const int LOG = 2048000;

    for (int i = blockIdx.x * blockDim.x + tid; i < TOT;
         i += gridDim.x * blockDim.x) {
        float4 v;
        if (i < LOG) v = sL4[i % 250];
        else         v = sF4[(i - LOG) & 31];
        out4[i] = v;
    }
}

// ================================ launch ===================================

extern "C" void kernel_launch(void* const* d_in, const int* in_sizes, int n_in,
                              void* d_out, int out_size, void* d_ws, size_t ws_size,
                              hipStream_t stream) {
    (void)in_sizes; (void)n_in; (void)out_size; (void)ws_size;

    const float* w_e1  = (const float*)d_in[7];
    const float* b_e1  = (const float*)d_in[8];
    const float* w_pw  = (const float*)d_in[14];
    const float* bnpw_g = (const float*)d_in[15];
    const float* bnpw_b = (const float*)d_in[16];
    const float* bnpw_m = (const float*)d_in[17];
    const float* bnpw_v = (const float*)d_in[18];
    const float* bnf_g = (const float*)d_in[19];
    const float* bnf_b = (const float*)d_in[20];
    const float* bnf_m = (const float*)d_in[21];
    const float* bnf_v = (const float*)d_in[22];
    const float* w1    = (const float*)d_in[23];
    const float* b1    = (const float*)d_in[24];
    const float* bnc_g = (const float*)d_in[25];
    const float* bnc_b = (const float*)d_in[26];
    const float* bnc_m = (const float*)d_in[27];
    const float* bnc_v = (const float*)d_in[28];
    const float* w2    = (const float*)d_in[29];
    const float* b2    = (const float*)d_in[30];

    float* ws  = (float*)d_ws;
    float* out = (float*)d_out;

    void* args[] = {
        (void*)&w_e1, (void*)&b_e1, (void*)&w_pw,
        (void*)&bnpw_g, (void*)&bnpw_b, (void*)&bnpw_m, (void*)&bnpw_v,
        (void*)&bnf_g, (void*)&bnf_b, (void*)&bnf_m, (void*)&bnf_v,
        (void*)&w1, (void*)&b1,
        (void*)&bnc_g, (void*)&bnc_b, (void*)&bnc_m, (void*)&bnc_v,
        (void*)&w2, (void*)&b2,
        (void*)&ws, (void*)&out,
    };

    hipError_t err = hipLaunchCooperativeKernel(
        reinterpret_cast<const void*>(&fused_all),
        dim3(1024), dim3(256), args, 0, stream);

    if (err != hipSuccess) {
        // deterministic fallback: proven 3-kernel chain
        hipLaunchKernelGGL(feat_kernel, dim3(128), dim3(256), 0, stream,
                           w_e1, b_e1, w_pw,
                           bnpw_g, bnpw_b, bnpw_m, bnpw_v,
                           bnf_g, bnf_b, bnf_m, bnf_v,
                           w1, b1,
                           bnc_g, bnc_b, bnc_m, bnc_v, ws);
        hipLaunchKernelGGL(logits_kernel, dim3(250), dim3(256), 0, stream,
                           w2, b2, ws);
        hipLaunchKernelGGL(broadcast_out, dim3(2048), dim3(256), 0, stream,
                           ws, out);
    }
}

// Round 4
// 157.848 us; speedup vs baseline: 2.3541x; 2.3541x over previous
//
#include <hip/hip_runtime.h>

#define BNEPS 1e-5f

// ---------------------------------------------------------------------------
// The reference network's output is batch-constant: binarize(relu(x)) == +1
// everywhere, so the fire module's outputs are data-independent. We compute
// feat F[128] and logits L[1000] once, then broadcast over the 8192 rows.
//
// Single fused dispatch. Cross-block deps use a hand-rolled producer->consumer
// flag protocol with agent-scope atomics (CG grid.sync measured ~180us/sync on
// gfx950 in R3 -- unusable). All 1024 blocks are co-resident by construction:
// __launch_bounds__(256,4) and 1024 = 4 blocks/CU * 256 CU, so producers are
// guaranteed to run regardless of dispatch order.
//
// ws layout (floats): [0..1000) L | [1024..1152) F | [1152..1280) Cc
// flags (uint32): ws_u32[4096] = flag1 (feat done), ws_u32[4128] = flag2
// (logits done). Reset to 0 by a hipMemsetAsync node at the start of every
// call (graph-capturable), so every call performs identical work.
// ---------------------------------------------------------------------------

#define AG __HIP_MEMORY_SCOPE_AGENT

__device__ __forceinline__ float wave_reduce(float acc) {
    #pragma unroll
    for (int off = 32; off > 0; off >>= 1)
        acc += __shfl_down(acc, off);
    return acc;
}

__global__ __launch_bounds__(256, 4) void fused_all(
    const float* __restrict__ w_e1, const float* __restrict__ b_e1,
    const float* __restrict__ w_pw,
    const float* __restrict__ bnpw_g, const float* __restrict__ bnpw_b,
    const float* __restrict__ bnpw_m, const float* __restrict__ bnpw_v,
    const float* __restrict__ bnf_g, const float* __restrict__ bnf_b,
    const float* __restrict__ bnf_m, const float* __restrict__ bnf_v,
    const float* __restrict__ w1, const float* __restrict__ b1,
    const float* __restrict__ bnc_g, const float* __restrict__ bnc_b,
    const float* __restrict__ bnc_m, const float* __restrict__ bnc_v,
    const float* __restrict__ w2, const float* __restrict__ b2,
    float* __restrict__ ws, float* __restrict__ out)
{
    __shared__ __align__(16) float e1c[128];
    __shared__ __align__(16) float e3c[128];
    __shared__ __align__(16) float hb[2304];
    __shared__ __align__(16) float sC[128];
    __shared__ __align__(16) float sL[1000];
    __shared__ __align__(16) float sF[128];
    __shared__ float red[4];

    const int tid = threadIdx.x;
    const int bid = blockIdx.x;

    unsigned int* flag1 = reinterpret_cast<unsigned int*>(ws) + 4096;
    unsigned int* flag2 = reinterpret_cast<unsigned int*>(ws) + 4128;

    // ---- phase A: blocks 0..127 compute F[o], Cc[o] ----
    if (bid < 128) {
        const int o = bid;
        if (tid < 128) {
            const float4* we = reinterpret_cast<const float4*>(w_e1 + tid * 32);
            const float4* wp = reinterpret_cast<const float4*>(w_pw + tid * 32);
            float s = 0.f, p = 0.f;
            #pragma unroll
            for (int q = 0; q < 8; ++q) {
                float4 a = we[q], b = wp[q];
                s += ((a.x >= 0.f) ? 1.f : -1.f) + ((a.y >= 0.f) ? 1.f : -1.f)
                   + ((a.z >= 0.f) ? 1.f : -1.f) + ((a.w >= 0.f) ? 1.f : -1.f);
                p += ((b.x >= 0.f) ? 1.f : -1.f) + ((b.y >= 0.f) ? 1.f : -1.f)
                   + ((b.z >= 0.f) ? 1.f : -1.f) + ((b.w >= 0.f) ? 1.f : -1.f);
            }
            e1c[tid] = fmaxf(s + b_e1[tid], 0.f);
            float inv = bnpw_g[tid] * rsqrtf(bnpw_v[tid] + BNEPS);
            e3c[tid] = fmaxf((p - bnpw_m[tid]) * inv + bnpw_b[tid], 0.f);
        }
        __syncthreads();

        #pragma unroll
        for (int r = 0; r < 9; ++r) {
            int f = r * 256 + tid;
            int ch = f / 9;
            float v = (ch < 128) ? e1c[ch] : e3c[ch - 128];
            float inv = bnf_g[f] * rsqrtf(bnf_v[f] + BNEPS);
            hb[f] = (v - bnf_m[f]) * inv + bnf_b[f];
        }
        __syncthreads();

        const float4* __restrict__ w1r = reinterpret_cast<const float4*>(w1 + o * 2304);
        const float4* __restrict__ hb4 = reinterpret_cast<const float4*>(hb);
        float acc = 0.f;
        for (int j = tid; j < 576; j += 256) {
            float4 w = w1r[j];
            float4 h = hb4[j];
            acc += w.x * h.x + w.y * h.y + w.z * h.z + w.w * h.w;
        }
        acc = wave_reduce(acc);
        const int lane = tid & 63, wave = tid >> 6;
        if (lane == 0) red[wave] = acc;
        __syncthreads();
        if (tid == 0) {
            float F = (red[0] + red[1]) + (red[2] + red[3]) + b1[o];
            __hip_atomic_store(&ws[1024 + o], F, __ATOMIC_RELAXED, AG);
            float r = fmaxf(F, 0.f);
            float inv = bnc_g[o] * rsqrtf(bnc_v[o] + BNEPS);
            float Cc = (r - bnc_m[o]) * inv + bnc_b[o];
            __hip_atomic_store(&ws[1152 + o], Cc, __ATOMIC_RELAXED, AG);
            __hip_atomic_fetch_add(flag1, 1u, __ATOMIC_RELEASE, AG);
        }
    }

    // ---- phase B: blocks 128..377 compute logits, one wave per logit ----
    if (bid >= 128 && bid < 378) {
        if (tid == 0) {
            while (__hip_atomic_load(flag1, __ATOMIC_ACQUIRE, AG) < 128u)
                __builtin_amdgcn_s_sleep(2);
        }
        __syncthreads();
        if (tid < 128)
            sC[tid] = __hip_atomic_load(&ws[1152 + tid], __ATOMIC_RELAXED, AG);
        __syncthreads();

        const int lane = tid & 63, wave = tid >> 6;
        const int n = (bid - 128) * 4 + wave;   // 250*4 = 1000
        float2 w = reinterpret_cast<const float2*>(w2 + n * 128)[lane];
        float acc = w.x * sC[2 * lane] + w.y * sC[2 * lane + 1];
        acc = wave_reduce(acc);
        if (lane == 0)
            __hip_atomic_store(&ws[n], acc + b2[n], __ATOMIC_RELAXED, AG);
        __syncthreads();
        if (tid == 0)
            __hip_atomic_fetch_add(flag2, 1u, __ATOMIC_RELEASE, AG);
    }

    // ---- phase C: all blocks broadcast ----
    if (tid == 0) {
        while (__hip_atomic_load(flag2, __ATOMIC_ACQUIRE, AG) < 250u)
            __builtin_amdgcn_s_sleep(2);
    }
    __syncthreads();

    for (int i = tid; i < 1000; i += 256)
        sL[i] = __hip_atomic_load(&ws[i], __ATOMIC_RELAXED, AG);
    if (tid < 128)
        sF[tid] = __hip_atomic_load(&ws[1024 + tid], __ATOMIC_RELAXED, AG);
    __syncthreads();

    const float4* sL4 = reinterpret_cast<const float4*>(sL);
    const float4* sF4 = reinterpret_cast<const float4*>(sF);
    float4* out4 = reinterpret_cast<float4*>(out);

    const int TOT = 2310144;   // 9,240,576 floats / 4
    const int LOG = 2048000;   // 8,192,000 floats / 4 (logits section)

    for (int i = bid * 256 + tid; i < TOT; i += 1024 * 256) {
        float4 v;
        if (i < LOG) v = sL4[i % 250];          // 250 float4 per logits row
        else         v = sF4[(i - LOG) & 31];   // 32 float4 per feat row
        out4[i] = v;
    }
}

// ================================ launch ===================================

extern "C" void kernel_launch(void* const* d_in, const int* in_sizes, int n_in,
                              void* d_out, int out_size, void* d_ws, size_t ws_size,
                              hipStream_t stream) {
    (void)in_sizes; (void)n_in; (void)out_size; (void)ws_size;

    const float* w_e1  = (const float*)d_in[7];
    const float* b_e1  = (const float*)d_in[8];
    const float* w_pw  = (const float*)d_in[14];
    const float* bnpw_g = (const float*)d_in[15];
    const float* bnpw_b = (const float*)d_in[16];
    const float* bnpw_m = (const float*)d_in[17];
    const float* bnpw_v = (const float*)d_in[18];
    const float* bnf_g = (const float*)d_in[19];
    const float* bnf_b = (const float*)d_in[20];
    const float* bnf_m = (const float*)d_in[21];
    const float* bnf_v = (const float*)d_in[22];
    const float* w1    = (const float*)d_in[23];
    const float* b1    = (const float*)d_in[24];
    const float* bnc_g = (const float*)d_in[25];
    const float* bnc_b = (const float*)d_in[26];
    const float* bnc_m = (const float*)d_in[27];
    const float* bnc_v = (const float*)d_in[28];
    const float* w2    = (const float*)d_in[29];
    const float* b2    = (const float*)d_in[30];

    float* ws  = (float*)d_ws;
    float* out = (float*)d_out;

    // reset the two flag counters (and padding) to zero each call
    hipMemsetAsync((char*)d_ws + 4096 * sizeof(float), 0, 256, stream);

    hipLaunchKernelGGL(fused_all, dim3(1024), dim3(256), 0, stream,
                       w_e1, b_e1, w_pw,
                       bnpw_g, bnpw_b, bnpw_m, bnpw_v,
                       bnf_g, bnf_b, bnf_m, bnf_v,
                       w1, b1,
                       bnc_g, bnc_b, bnc_m, bnc_v,
                       w2, b2, ws, out);
}

// Round 5
// 29.905 us; speedup vs baseline: 12.4255x; 5.2783x over previous
//
#include <hip/hip_runtime.h>

#define BNEPS 1e-5f

// ---------------------------------------------------------------------------
// The reference network's output is batch-constant: binarize(relu(x)) == +1
// everywhere, so the fire module's outputs are data-independent. We compute
// feat F[128] and logits L[1000] once, then broadcast over the 8192 rows.
//
// Sync strategy (measured): CG grid.sync ~180us/sync (R3), single-flag spin
// with 1024 pollers ~70us/phase (R4) -> dispatch boundaries (~2-4us) are the
// only cheap device-wide sync. Two dispatches:
//   1) feat_logits: 128 blocks; block o computes F[o], Cc[o], then adds its
//      owned contribution w2[:,o]*Cc[o] into int64 fixed-point accumulators
//      (scale 2^40). Integer atomics are associative -> bit-deterministic.
//   2) broadcast: converts Lacc -> L (+b2) and streams the 36.96 MB output.
//
// ws layout: bytes [0..8000) int64 Lacc[1000] (zeroed each call by
// hipMemsetAsync); floats ws[2048..2176) = F[128].
// ---------------------------------------------------------------------------

__device__ __forceinline__ float wave_reduce(float acc) {
    #pragma unroll
    for (int off = 32; off > 0; off >>= 1)
        acc += __shfl_down(acc, off);
    return acc;
}

__global__ __launch_bounds__(256) void feat_logits_kernel(
    const float* __restrict__ w_e1, const float* __restrict__ b_e1,
    const float* __restrict__ w_pw,
    const float* __restrict__ bnpw_g, const float* __restrict__ bnpw_b,
    const float* __restrict__ bnpw_m, const float* __restrict__ bnpw_v,
    const float* __restrict__ bnf_g, const float* __restrict__ bnf_b,
    const float* __restrict__ bnf_m, const float* __restrict__ bnf_v,
    const float* __restrict__ w1, const float* __restrict__ b1,
    const float* __restrict__ bnc_g, const float* __restrict__ bnc_b,
    const float* __restrict__ bnc_m, const float* __restrict__ bnc_v,
    const float* __restrict__ w2,
    float* __restrict__ ws)
{
    __shared__ __align__(16) float e1c[128];
    __shared__ __align__(16) float e3c[128];
    __shared__ __align__(16) float hb[2304];
    __shared__ float red[4];
    __shared__ float sCc;

    const int tid = threadIdx.x;
    const int o = blockIdx.x;          // 0..127

    // channel constants after squeeze (binarized inputs are all +1)
    if (tid < 128) {
        const float4* we = reinterpret_cast<const float4*>(w_e1 + tid * 32);
        const float4* wp = reinterpret_cast<const float4*>(w_pw + tid * 32);
        float s = 0.f, p = 0.f;
        #pragma unroll
        for (int q = 0; q < 8; ++q) {
            float4 a = we[q], b = wp[q];
            s += ((a.x >= 0.f) ? 1.f : -1.f) + ((a.y >= 0.f) ? 1.f : -1.f)
               + ((a.z >= 0.f) ? 1.f : -1.f) + ((a.w >= 0.f) ? 1.f : -1.f);
            p += ((b.x >= 0.f) ? 1.f : -1.f) + ((b.y >= 0.f) ? 1.f : -1.f)
               + ((b.z >= 0.f) ? 1.f : -1.f) + ((b.w >= 0.f) ? 1.f : -1.f);
        }
        e1c[tid] = fmaxf(s + b_e1[tid], 0.f);
        float inv = bnpw_g[tid] * rsqrtf(bnpw_v[tid] + BNEPS);
        e3c[tid] = fmaxf((p - bnpw_m[tid]) * inv + bnpw_b[tid], 0.f);
    }
    __syncthreads();

    // hb = BN1d_2304(flatten(concat(e1,e3)))
    #pragma unroll
    for (int r = 0; r < 9; ++r) {
        int f = r * 256 + tid;
        int ch = f / 9;
        float v = (ch < 128) ? e1c[ch] : e3c[ch - 128];
        float inv = bnf_g[f] * rsqrtf(bnf_v[f] + BNEPS);
        hb[f] = (v - bnf_m[f]) * inv + bnf_b[f];
    }
    __syncthreads();

    // F[o] = hb . w1[o] + b1[o]
    const float4* __restrict__ w1r = reinterpret_cast<const float4*>(w1 + o * 2304);
    const float4* __restrict__ hb4 = reinterpret_cast<const float4*>(hb);
    float acc = 0.f;
    for (int j = tid; j < 576; j += 256) {
        float4 w = w1r[j];
        float4 h = hb4[j];
        acc += w.x * h.x + w.y * h.y + w.z * h.z + w.w * h.w;
    }
    acc = wave_reduce(acc);
    const int lane = tid & 63, wave = tid >> 6;
    if (lane == 0) red[wave] = acc;
    __syncthreads();
    if (tid == 0) {
        float F = (red[0] + red[1]) + (red[2] + red[3]) + b1[o];
        ws[2048 + o] = F;                       // F for the broadcast
        float r = fmaxf(F, 0.f);
        float inv = bnc_g[o] * rsqrtf(bnc_v[o] + BNEPS);
        sCc = (r - bnc_m[o]) * inv + bnc_b[o];  // Cc[o], owned by this block
    }
    __syncthreads();
    const float Cc_o = sCc;

    // logits partial: Lacc[n] += round(w2[n,o] * Cc[o] * 2^40)  (int64, exact)
    unsigned long long* Lacc = reinterpret_cast<unsigned long long*>(ws);
    #pragma unroll
    for (int k = 0; k < 4; ++k) {
        int n = tid + 256 * k;
        if (n < 1000) {
            float v = w2[n * 128 + o] * Cc_o * 0x1p40f;
            long long q = __float2ll_rn(v);
            atomicAdd(&Lacc[n], (unsigned long long)q);
        }
    }
}

// Broadcast: out[0 .. 8192*1000) = L per row; then 8192*128 of F per row.
__global__ __launch_bounds__(256) void broadcast_out(
    const float* __restrict__ ws, const float* __restrict__ b2,
    float* __restrict__ out)
{
    __shared__ __align__(16) float sL[1000];
    __shared__ __align__(16) float sF[128];
    const int tid = threadIdx.x;

    const long long* __restrict__ Lacc = reinterpret_cast<const long long*>(ws);
    for (int i = tid; i < 1000; i += 256)
        sL[i] = fmaf((float)Lacc[i], 0x1p-40f, b2[i]);
    if (tid < 128) sF[tid] = ws[2048 + tid];
    __syncthreads();

    const float4* sL4 = reinterpret_cast<const float4*>(sL);
    const float4* sF4 = reinterpret_cast<const float4*>(sF);
    float4* out4 = reinterpret_cast<float4*>(out);

    const int TOT = 2310144;   // 9,240,576 floats / 4
    const int LOG = 2048000;   // 8,192,000 floats / 4 (logits section)

    for (int i = blockIdx.x * blockDim.x + tid; i < TOT;
         i += gridDim.x * blockDim.x) {
        float4 v;
        if (i < LOG) v = sL4[i % 250];          // 250 float4 per logits row
        else         v = sF4[(i - LOG) & 31];   // 32 float4 per feat row
        out4[i] = v;
    }
}

// ================================ launch ===================================

extern "C" void kernel_launch(void* const* d_in, const int* in_sizes, int n_in,
                              void* d_out, int out_size, void* d_ws, size_t ws_size,
                              hipStream_t stream) {
    (void)in_sizes; (void)n_in; (void)out_size; (void)ws_size;

    const float* w_e1  = (const float*)d_in[7];
    const float* b_e1  = (const float*)d_in[8];
    const float* w_pw  = (const float*)d_in[14];
    const float* bnpw_g = (const float*)d_in[15];
    const float* bnpw_b = (const float*)d_in[16];
    const float* bnpw_m = (const float*)d_in[17];
    const float* bnpw_v = (const float*)d_in[18];
    const float* bnf_g = (const float*)d_in[19];
    const float* bnf_b = (const float*)d_in[20];
    const float* bnf_m = (const float*)d_in[21];
    const float* bnf_v = (const float*)d_in[22];
    const float* w1    = (const float*)d_in[23];
    const float* b1    = (const float*)d_in[24];
    const float* bnc_g = (const float*)d_in[25];
    const float* bnc_b = (const float*)d_in[26];
    const float* bnc_m = (const float*)d_in[27];
    const float* bnc_v = (const float*)d_in[28];
    const float* w2    = (const float*)d_in[29];
    const float* b2    = (const float*)d_in[30];

    float* ws  = (float*)d_ws;
    float* out = (float*)d_out;

    // zero the int64 logit accumulators (first 8000 bytes) every call
    hipMemsetAsync(d_ws, 0, 8000, stream);

    hipLaunchKernelGGL(feat_logits_kernel, dim3(128), dim3(256), 0, stream,
                       w_e1, b_e1, w_pw,
                       bnpw_g, bnpw_b, bnpw_m, bnpw_v,
                       bnf_g, bnf_b, bnf_m, bnf_v,
                       w1, b1,
                       bnc_g, bnc_b, bnc_m, bnc_v,
                       w2, ws);

    hipLaunchKernelGGL(broadcast_out, dim3(2048), dim3(256), 0, stream,
                       ws, b2, out);
}

// Round 6
// 20.873 us; speedup vs baseline: 17.8019x; 1.4327x over previous
//
#include <hip/hip_runtime.h>

#define BNEPS 1e-5f

// ---------------------------------------------------------------------------
// The reference network's output is batch-constant: binarize(relu(x)) == +1
// everywhere, so the fire module's outputs are data-independent. We compute
// feat F[128] and logits L[1000] once, then broadcast over the 8192 rows.
//
// Measured sync costs on this harness: CG grid.sync ~180us (R3), 1k-poller
// flag spin ~70us/phase (R4), int64-atomic fan-in + memset dependency ~+6us
// (R5). Dispatch boundaries (~1-2us) are the cheapest device-wide sync.
//
// Structure (3 dispatches, no atomics, no memset, fully deterministic):
//   K1 feat_partial: 512 blocks = 4 K-splits x 128 outputs. Block (s,o)
//      computes partial_s[o] = w1[o, s*576:(s+1)*576] . hb[slice] and writes
//      ws[s*128+o]. Each block touches only ~20 KB -> ~1 latency round.
//   K2 logits: 250 blocks; re-sums partials (fixed order), bnc -> Cc, one
//      wave per logit; writes L to ws[1024+n].
//   K3 broadcast: re-sums partials for F (same fixed order -> bitwise equal),
//      reads L, streams the 36.96 MB output.
//
// ws layout (floats): [0..512) partials | [1024..2024) L
// ---------------------------------------------------------------------------

__device__ __forceinline__ float wave_reduce(float acc) {
    #pragma unroll
    for (int off = 32; off > 0; off >>= 1)
        acc += __shfl_down(acc, off);
    return acc;
}

// ------------------------------- K1 ----------------------------------------

__global__ __launch_bounds__(256) void feat_partial_kernel(
    const float* __restrict__ w_e1, const float* __restrict__ b_e1,
    const float* __restrict__ w_pw,
    const float* __restrict__ bnpw_g, const float* __restrict__ bnpw_b,
    const float* __restrict__ bnpw_m, const float* __restrict__ bnpw_v,
    const float* __restrict__ bnf_g, const float* __restrict__ bnf_b,
    const float* __restrict__ bnf_m, const float* __restrict__ bnf_v,
    const float* __restrict__ w1,
    float* __restrict__ ws)
{
    __shared__ __align__(16) float cst[64];    // channel consts for this slice
    __shared__ __align__(16) float hbs[576];   // hb slice
    __shared__ float red[4];

    const int tid = threadIdx.x;
    const int s   = blockIdx.x & 3;            // K-split 0..3
    const int o   = blockIdx.x >> 2;           // output 0..127
    const int f0  = s * 576;                   // f-range base
    const int ch0 = s * 64;                    // channel base

    // hoist the w1 slice load (independent of everything below)
    float4 wreg = make_float4(0.f, 0.f, 0.f, 0.f);
    if (tid < 144)
        wreg = reinterpret_cast<const float4*>(w1 + o * 2304 + f0)[tid];

    // channel constants for the 64 channels of this slice
    if (tid < 64) {
        const int ch = ch0 + tid;
        float r;
        if (ch < 128) {
            const float4* we = reinterpret_cast<const float4*>(w_e1 + ch * 32);
            float ssum = 0.f;
            #pragma unroll
            for (int q = 0; q < 8; ++q) {
                float4 a = we[q];
                ssum += ((a.x >= 0.f) ? 1.f : -1.f) + ((a.y >= 0.f) ? 1.f : -1.f)
                      + ((a.z >= 0.f) ? 1.f : -1.f) + ((a.w >= 0.f) ? 1.f : -1.f);
            }
            r = fmaxf(ssum + b_e1[ch], 0.f);
        } else {
            const int c2 = ch - 128;
            const float4* wp = reinterpret_cast<const float4*>(w_pw + c2 * 32);
            float psum = 0.f;
            #pragma unroll
            for (int q = 0; q < 8; ++q) {
                float4 a = wp[q];
                psum += ((a.x >= 0.f) ? 1.f : -1.f) + ((a.y >= 0.f) ? 1.f : -1.f)
                      + ((a.z >= 0.f) ? 1.f : -1.f) + ((a.w >= 0.f) ? 1.f : -1.f);
            }
            float inv = bnpw_g[c2] * rsqrtf(bnpw_v[c2] + BNEPS);
            r = fmaxf((psum - bnpw_m[c2]) * inv + bnpw_b[c2], 0.f);
        }
        cst[tid] = r;
    }
    __syncthreads();

    // hb slice: 576 values (thread t handles fl = t, t+256, t+512<576)
    #pragma unroll
    for (int r = 0; r < 3; ++r) {
        int fl = tid + 256 * r;
        if (fl < 576) {
            int f = f0 + fl;
            float v = cst[fl / 9];
            float inv = bnf_g[f] * rsqrtf(bnf_v[f] + BNEPS);
            hbs[fl] = (v - bnf_m[f]) * inv + bnf_b[f];
        }
    }
    __syncthreads();

    // partial dot: 144 float4 terms
    float acc = 0.f;
    if (tid < 144) {
        float4 h = reinterpret_cast<const float4*>(hbs)[tid];
        acc = wreg.x * h.x + wreg.y * h.y + wreg.z * h.z + wreg.w * h.w;
    }
    acc = wave_reduce(acc);
    const int lane = tid & 63, wave = tid >> 6;
    if (lane == 0) red[wave] = acc;
    __syncthreads();
    if (tid == 0)
        ws[s * 128 + o] = (red[0] + red[1]) + (red[2] + red[3]);
}

// ------------------------------- K2 ----------------------------------------

__global__ __launch_bounds__(256) void logits_kernel(
    const float* __restrict__ b1,
    const float* __restrict__ bnc_g, const float* __restrict__ bnc_b,
    const float* __restrict__ bnc_m, const float* __restrict__ bnc_v,
    const float* __restrict__ w2, const float* __restrict__ b2,
    float* __restrict__ ws)
{
    __shared__ __align__(16) float sC[128];
    const int tid = threadIdx.x;

    // hoist w2 loads (independent of ws)
    const int lane = tid & 63, wave = tid >> 6;
    const int n = blockIdx.x * 4 + wave;   // 250*4 = 1000
    float2 w = reinterpret_cast<const float2*>(w2 + n * 128)[lane];

    if (tid < 128) {
        // fixed-order partial sum -- must match K3's expression exactly
        float F = ((ws[tid] + ws[128 + tid]) + (ws[256 + tid] + ws[384 + tid]))
                  + b1[tid];
        float r = fmaxf(F, 0.f);
        float inv = bnc_g[tid] * rsqrtf(bnc_v[tid] + BNEPS);
        sC[tid] = (r - bnc_m[tid]) * inv + bnc_b[tid];
    }
    __syncthreads();

    float acc = w.x * sC[2 * lane] + w.y * sC[2 * lane + 1];
    acc = wave_reduce(acc);
    if (lane == 0) ws[1024 + n] = acc + b2[n];
}

// ------------------------------- K3 ----------------------------------------

__global__ __launch_bounds__(256) void broadcast_out(
    const float* __restrict__ ws, const float* __restrict__ b1,
    float* __restrict__ out)
{
    __shared__ __align__(16) float sL[1000];
    __shared__ __align__(16) float sF[128];
    const int tid = threadIdx.x;

    for (int i = tid; i < 1000; i += 256) sL[i] = ws[1024 + i];
    if (tid < 128) {
        // same fixed-order sum as K2 -> bitwise-identical F
        sF[tid] = ((ws[tid] + ws[128 + tid]) + (ws[256 + tid] + ws[384 + tid]))
                  + b1[tid];
    }
    __syncthreads();

    const float4* sL4 = reinterpret_cast<const float4*>(sL);
    const float4* sF4 = reinterpret_cast<const float4*>(sF);
    float4* out4 = reinterpret_cast<float4*>(out);

    const int TOT = 2310144;   // 9,240,576 floats / 4
    const int LOG = 2048000;   // 8,192,000 floats / 4 (logits section)

    for (int i = blockIdx.x * blockDim.x + tid; i < TOT;
         i += gridDim.x * blockDim.x) {
        float4 v;
        if (i < LOG) v = sL4[i % 250];          // 250 float4 per logits row
        else         v = sF4[(i - LOG) & 31];   // 32 float4 per feat row
        out4[i] = v;
    }
}

// ================================ launch ===================================

extern "C" void kernel_launch(void* const* d_in, const int* in_sizes, int n_in,
                              void* d_out, int out_size, void* d_ws, size_t ws_size,
                              hipStream_t stream) {
    (void)in_sizes; (void)n_in; (void)out_size; (void)ws_size;

    const float* w_e1  = (const float*)d_in[7];
    const float* b_e1  = (const float*)d_in[8];
    const float* w_pw  = (const float*)d_in[14];
    const float* bnpw_g = (const float*)d_in[15];
    const float* bnpw_b = (const float*)d_in[16];
    const float* bnpw_m = (const float*)d_in[17];
    const float* bnpw_v = (const float*)d_in[18];
    const float* bnf_g = (const float*)d_in[19];
    const float* bnf_b = (const float*)d_in[20];
    const float* bnf_m = (const float*)d_in[21];
    const float* bnf_v = (const float*)d_in[22];
    const float* w1    = (const float*)d_in[23];
    const float* b1    = (const float*)d_in[24];
    const float* bnc_g = (const float*)d_in[25];
    const float* bnc_b = (const float*)d_in[26];
    const float* bnc_m = (const float*)d_in[27];
    const float* bnc_v = (const float*)d_in[28];
    const float* w2    = (const float*)d_in[29];
    const float* b2    = (const float*)d_in[30];

    float* ws  = (float*)d_ws;
    float* out = (float*)d_out;

    hipLaunchKernelGGL(feat_partial_kernel, dim3(512), dim3(256), 0, stream,
                       w_e1, b_e1, w_pw,
                       bnpw_g, bnpw_b, bnpw_m, bnpw_v,
                       bnf_g, bnf_b, bnf_m, bnf_v,
                       w1, ws);

    hipLaunchKernelGGL(logits_kernel, dim3(250), dim3(256), 0, stream,
                       b1, bnc_g, bnc_b, bnc_m, bnc_v, w2, b2, ws);

    hipLaunchKernelGGL(broadcast_out, dim3(2048), dim3(256), 0, stream,
                       ws, b1, out);
}